// Round 2
// baseline (217.381 us; speedup 1.0000x reference)
//
#include <hip/hip_runtime.h>
#include <hip/hip_bf16.h>

#define N_ 2048
#define D_ 128
#define B_ 8
#define VROWS 144                // 130 useful cols (128 emb + hsq + 1) padded
#define NBLK (B_ * (N_ / 32))    // 512 blocks, 32 adj rows each
#define BKS 64                   // K per step
#define NKS (N_ / BKS)           // 32 steps

typedef __attribute__((ext_vector_type(8))) short short8;
typedef __attribute__((ext_vector_type(4))) float f32x4;

__device__ __forceinline__ unsigned short f2bf(float x) {
  unsigned int u = __builtin_bit_cast(unsigned int, x);
  u += 0x7fffu + ((u >> 16) & 1u);   // RNE; inputs finite
  return (unsigned short)(u >> 16);
}

__device__ __forceinline__ short8 pack8(float4 a, float4 b) {
  short8 r;
  r[0] = (short)f2bf(a.x); r[1] = (short)f2bf(a.y);
  r[2] = (short)f2bf(a.z); r[3] = (short)f2bf(a.w);
  r[4] = (short)f2bf(b.x); r[5] = (short)f2bf(b.y);
  r[6] = (short)f2bf(b.z); r[7] = (short)f2bf(b.w);
  return r;
}

__device__ __forceinline__ void async_lds16(const void* g, void* l) {
  __builtin_amdgcn_global_load_lds(
      (const __attribute__((address_space(1))) void*)g,
      (__attribute__((address_space(3))) void*)l, 16, 0, 0);
}

// Stage one 144x64 bf16 VT tile batch into an LDS buffer, XOR-swizzled in 16B
// units (realized by permuting per-lane GLOBAL source; LDS dest stays linear).
template <int CNT>
__device__ __forceinline__ void stage_vt(const unsigned short* vtsrc, int jk,
                                         unsigned short* bufp, int wstart,
                                         int lane) {
#pragma unroll
  for (int i = 0; i < CNT; ++i) {
    int u = wstart + i * 64 + lane;       // 16B unit index, 8 units/row
    int r = u >> 3, up2 = u & 7;
    int ul = up2 ^ (r & 7);
    async_lds16(vtsrc + (size_t)r * N_ + jk + ul * 8,
                (char*)bufp + (size_t)(wstart + i * 64) * 16);
  }
}

// Build VT[b][144][2048] bf16 (row d: d<128 -> emb[:,d]; 128 -> hsq; 129 -> 1;
// >=130 -> 0) and hsq[b][2048] fp32. One block per 64 nodes. (verified)
__global__ __launch_bounds__(256) void prep_kernel(
    const float* __restrict__ emb, unsigned short* __restrict__ vt,
    float* __restrict__ hsq) {
  __shared__ float semb[64 * 132];
  __shared__ float shsq[64];
  const int t = threadIdx.x;
  const int bb = blockIdx.x >> 5;
  const int j0 = (blockIdx.x & 31) << 6;
  const float* ebase = emb + ((size_t)(bb * N_ + j0)) * D_;
#pragma unroll
  for (int it = 0; it < 8; ++it) {
    int fidx = it * 1024 + t * 4;
    int j = fidx >> 7, d = fidx & 127;
    const float4 v = *(const float4*)(ebase + (size_t)j * D_ + d);
    *(float4*)&semb[j * 132 + d] = v;
  }
  __syncthreads();
  {
    int j = t >> 2, q = t & 3;
    const float* row = &semb[j * 132 + q * 32];
    float p = 0.f;
#pragma unroll
    for (int x = 0; x < 32; ++x) p += row[x] * row[x];
    p += __shfl_down(p, 2);
    p += __shfl_down(p, 1);
    if (q == 0) { shsq[j] = p; hsq[bb * N_ + j0 + j] = p; }
  }
  __syncthreads();
  unsigned short* vbase = vt + (size_t)bb * VROWS * N_ + j0;
#pragma unroll
  for (int it = 0; it < 36; ++it) {
    int idx = it * 256 + t;
    int d = idx >> 6, j = idx & 63;
    float val;
    if (d < 128)      val = semb[j * 132 + d];
    else if (d == 128) val = shsq[j];
    else if (d == 129) val = 1.0f;
    else               val = 0.0f;
    vbase[(size_t)d * N_ + j] = f2bf(val);
  }
}

// One pipeline step: counted-vmcnt wait (batch ki retired; ki+1,ki+2 stay in
// flight), barrier, THEN issue batch ki+3 (ring-safe: issue after barrier),
// then consume buf[U]. U/UI are compile-time slot literals (rule #20).
#define STEP(KI, U, UI, NW, ISS)                                              \
  {                                                                           \
    asm volatile("s_waitcnt vmcnt(" #NW ")" ::: "memory");                    \
    __builtin_amdgcn_s_barrier();                                             \
    __builtin_amdgcn_sched_barrier(0);                                        \
    if (ISS) {                                                                \
      const int nk = (KI) + 3;                                                \
      if (wlo) stage_vt<5>(vtbase, nk * BKS, &lV[UI][0], wstart, lane);       \
      else     stage_vt<4>(vtbase, nk * BKS, &lV[UI][0], wstart, lane);       \
      aA[UI] = *(const float4*)(arow + (size_t)nk * BKS);                     \
      aB[UI] = *(const float4*)(arow + (size_t)nk * BKS + 4);                 \
    }                                                                         \
    {                                                                         \
      short8 afrag = pack8(aA[U], aB[U]);                                     \
      __builtin_amdgcn_s_setprio(1);                                          \
      _Pragma("unroll")                                                       \
      for (int nt = 0; nt < 9; ++nt) {                                        \
        int rr2 = nt * 16 + lhalf;                                            \
        int upx = (kh * 4 + quad) ^ (rr2 & 7);                                \
        short8 bfv = *(const short8*)&lV[U][rr2 * BKS + upx * 8];             \
        acc[nt] =                                                             \
            __builtin_amdgcn_mfma_f32_16x16x32_bf16(afrag, bfv, acc[nt], 0, 0, 0); \
      }                                                                       \
      __builtin_amdgcn_s_setprio(0);                                          \
    }                                                                         \
  }

// Main GEMM: block = 32 adj rows, full contiguous 256 KB stream over K=2048.
// A: global -> registers, 4-slot rotation, 3 steps ahead. VT: 4 LDS buffers,
// global_load_lds, 3 batches in flight across barriers (counted vmcnt).
__global__ __launch_bounds__(256, 2) void gemm_kernel(
    const float* __restrict__ adj, const float* __restrict__ emb,
    const float* __restrict__ hsq, const unsigned short* __restrict__ vt,
    float* __restrict__ partials) {
  __shared__ unsigned short lV[4][VROWS * BKS];   // 4 x 18432 B = 73728 B
  __shared__ float red[4];

  const int t = threadIdx.x;
  const int lane = t & 63, wave = t >> 6;
  const int lhalf = lane & 15, quad = lane >> 4;
  const int mt = wave & 1;       // 16-row half
  const int kh = wave >> 1;      // 32-wide K-half of each BKS step
  const bool wlo = (wave < 2);
  // uneven unit split: 1152 16B units = 5+5+4+4 insts/lane across waves
  const int wstart = wlo ? wave * 320 : 640 + (wave - 2) * 256;

  // Bijective XCD swizzle: XCD x (= bid%8) gets batch x's 64 i-tiles,
  // so each XCD's L2 caches exactly one 590 KB VT.
  const int bid = blockIdx.x;
  const int rb = (bid & 7) * (NBLK / 8) + (bid >> 3);
  const int b = rb >> 6;
  const int i0 = (rb & 63) << 5;

  const float* abase = adj + ((size_t)b << 22);
  const unsigned short* vtbase = vt + (size_t)b * VROWS * N_;
  const float* arow =
      abase + (size_t)(i0 + mt * 16 + lhalf) * N_ + kh * 32 + quad * 8;

  f32x4 acc[9] = {};
  float4 aA[4], aB[4];

  // ---- prologue: issue batches 0,1,2 (order: VT(p) then A(p), fixed)
#pragma unroll
  for (int p = 0; p < 3; ++p) {
    if (wlo) stage_vt<5>(vtbase, p * BKS, &lV[p][0], wstart, lane);
    else     stage_vt<4>(vtbase, p * BKS, &lV[p][0], wstart, lane);
    aA[p] = *(const float4*)(arow + (size_t)p * BKS);
    aB[p] = *(const float4*)(arow + (size_t)p * BKS + 4);
  }

  // ---- main loop: steady-state vmcnt(12) keeps 2 full batches + issue in
  // flight across every barrier; never drains to 0 until the tail.
#pragma unroll 1
  for (int kb = 0; kb < 28; kb += 4) {
    STEP(kb + 0, 0, 3, 12, 1)
    STEP(kb + 1, 1, 0, 12, 1)
    STEP(kb + 2, 2, 1, 12, 1)
    STEP(kb + 3, 3, 2, 12, 1)
  }
  STEP(28, 0, 3, 12, 1)   // issues batch 31
  STEP(29, 1, 0, 12, 0)
  STEP(30, 2, 1, 6, 0)
  STEP(31, 3, 2, 0, 0)

  // ---- epilogue: part += acc[nt][rr] * U[i][d]; acc is K-partial per wave
  // (kh split) — linear, sums across waves via red[]. C/D: col=lane&15,
  // row=quad*4+rr.
  float part = 0.f;
  const float* erow_base = emb + (size_t)b * N_ * D_;
#pragma unroll
  for (int rr = 0; rr < 4; ++rr) {
    int i = i0 + mt * 16 + quad * 4 + rr;
    const float* erow = erow_base + (size_t)i * D_;
#pragma unroll
    for (int nt = 0; nt < 8; ++nt) {
      int d = nt * 16 + lhalf;
      part += acc[nt][rr] * (-2.0f * erow[d]);
    }
    float u8 = (lhalf == 0) ? 1.0f : (lhalf == 1) ? hsq[b * N_ + i] : 0.0f;
    part += acc[8][rr] * u8;
  }
#pragma unroll
  for (int off = 32; off > 0; off >>= 1) part += __shfl_down(part, off);
  if (lane == 0) red[wave] = part;
  __syncthreads();
  if (t == 0) partials[rb] = red[0] + red[1] + red[2] + red[3];
}

__global__ void finish_kernel(const float* __restrict__ partials,
                              float* __restrict__ out) {
  double s = 0.0;
  int t = threadIdx.x;
  for (int i = t; i < NBLK; i += 64) s += (double)partials[i];
#pragma unroll
  for (int off = 32; off > 0; off >>= 1) s += __shfl_down(s, off);
  if (t == 0) out[0] = (float)(s / (double)((size_t)B_ * N_));
}

extern "C" void kernel_launch(void* const* d_in, const int* in_sizes, int n_in,
                              void* d_out, int out_size, void* d_ws, size_t ws_size,
                              hipStream_t stream) {
  const float* adj = (const float*)d_in[0];
  const float* emb = (const float*)d_in[1];
  // ws layout: hsq (64 KiB) | VT bf16 (4.5 MiB) | partials (2 KiB)
  float* hsq = (float*)d_ws;
  unsigned short* vt = (unsigned short*)((char*)d_ws + 65536);
  float* partials = (float*)((char*)d_ws + 65536 + (size_t)B_ * VROWS * N_ * 2);

  prep_kernel<<<B_ * (N_ / 64), 256, 0, stream>>>(emb, vt, hsq);
  gemm_kernel<<<NBLK, 256, 0, stream>>>(adj, emb, hsq, vt, partials);
  finish_kernel<<<1, 64, 0, stream>>>(partials, (float*)d_out);
}

// Round 3
// 213.012 us; speedup vs baseline: 1.0205x; 1.0205x over previous
//
#include <hip/hip_runtime.h>
#include <hip/hip_bf16.h>

#define N_ 2048
#define D_ 128
#define B_ 8
#define DBLK 128                 // VT rows = emb dims only (hsq terms go via VALU)
#define BKS 64                   // K per step
#define KHALF 1024               // K range per block
#define NSTEP (KHALF / BKS)      // 16
#define NBLK (B_ * 64 * 2)       // 1024: batch x 64 i-tiles(32 rows) x 2 K-halves

typedef __attribute__((ext_vector_type(8))) short short8;
typedef __attribute__((ext_vector_type(4))) float f32x4;

__device__ __forceinline__ unsigned short f2bf(float x) {
  unsigned int u = __builtin_bit_cast(unsigned int, x);
  u += 0x7fffu + ((u >> 16) & 1u);   // RNE; inputs finite
  return (unsigned short)(u >> 16);
}

__device__ __forceinline__ short8 pack8(float4 a, float4 b) {
  short8 r;
  r[0] = (short)f2bf(a.x); r[1] = (short)f2bf(a.y);
  r[2] = (short)f2bf(a.z); r[3] = (short)f2bf(a.w);
  r[4] = (short)f2bf(b.x); r[5] = (short)f2bf(b.y);
  r[6] = (short)f2bf(b.z); r[7] = (short)f2bf(b.w);
  return r;
}

__device__ __forceinline__ void async_lds16(const void* g, void* l) {
  __builtin_amdgcn_global_load_lds(
      (const __attribute__((address_space(1))) void*)g,
      (__attribute__((address_space(3))) void*)l, 16, 0, 0);
}

// Stage one 128x64 bf16 VT tile (1024 16B units, 4/thread) into an LDS buffer.
// XOR swizzle in 16B units realized by permuting the per-lane GLOBAL source;
// LDS dest stays linear (global_load_lds requirement, verified structure).
__device__ __forceinline__ void stage_vt(const unsigned short* vtsrc, int jk,
                                         unsigned short* buf, int wave, int lane) {
#pragma unroll
  for (int i = 0; i < 4; ++i) {
    int u = i * 256 + wave * 64 + lane;   // unit index; 8 units per row
    int r = u >> 3, up2 = u & 7;
    int ul = up2 ^ (r & 7);
    async_lds16(vtsrc + (size_t)r * N_ + jk + ul * 8,
                (char*)buf + (size_t)(i * 256 + wave * 64) * 16);
  }
}

// Build VT[b][128][2048] bf16 (pure emb transpose) and hsq[b][2048] fp32.
// One block per 64 nodes. Also zeroes out[0] (gemm accumulates atomically).
__global__ __launch_bounds__(256) void prep_kernel(
    const float* __restrict__ emb, unsigned short* __restrict__ vt,
    float* __restrict__ hsq, float* __restrict__ out) {
  __shared__ float semb[64 * 132];   // stride 132 keeps float4 stores aligned
  __shared__ float shsq[64];
  const int t = threadIdx.x;
  if (blockIdx.x == 0 && t == 0) out[0] = 0.f;
  const int bb = blockIdx.x >> 5;
  const int j0 = (blockIdx.x & 31) << 6;
  const float* ebase = emb + ((size_t)(bb * N_ + j0)) * D_;
#pragma unroll
  for (int it = 0; it < 8; ++it) {
    int fidx = it * 1024 + t * 4;
    int j = fidx >> 7, d = fidx & 127;
    const float4 v = *(const float4*)(ebase + (size_t)j * D_ + d);
    *(float4*)&semb[j * 132 + d] = v;
  }
  __syncthreads();
  {
    int j = t >> 2, q = t & 3;
    const float* row = &semb[j * 132 + q * 32];
    float p = 0.f;
#pragma unroll
    for (int x = 0; x < 32; ++x) p += row[x] * row[x];
    p += __shfl_down(p, 2);
    p += __shfl_down(p, 1);
    if (q == 0) { shsq[j] = p; hsq[bb * N_ + j0 + j] = p; }
  }
  __syncthreads();
  // vectorized transpose-store: 1024 16B units (d, jgroup), 4 per thread
  unsigned short* vbase = vt + (size_t)bb * DBLK * N_ + j0;
#pragma unroll
  for (int it = 0; it < 4; ++it) {
    int u = it * 256 + t;
    int d = u >> 3, jg = u & 7;
    const float* sp = &semb[(size_t)jg * 8 * 132 + d];
    short8 pk;
#pragma unroll
    for (int x = 0; x < 8; ++x) pk[x] = (short)f2bf(sp[x * 132]);
    *(short8*)(vbase + (size_t)d * N_ + jg * 8) = pk;
  }
  (void)shsq;
}

// Main GEMM: block = 32 adj rows x 1024 K (contiguous 128 KB adj stream).
// R1-proven sync structure: one __syncthreads per step, prefetch (VT->LDS via
// global_load_lds + A->regs) issued at step top, in flight across compute.
// 4 blocks/CU (LDS 32.8 KB, VGPR-capped) for 16 waves/CU latency hiding.
// hsq cross terms (adj*hsq_j, adj*1) accumulate via VALU from in-reg A.
__global__ __launch_bounds__(256, 4) void gemm_kernel(
    const float* __restrict__ adj, const float* __restrict__ emb,
    const float* __restrict__ hsq, const unsigned short* __restrict__ vt,
    float* __restrict__ out) {
  __shared__ unsigned short lV[2][DBLK * BKS];   // 2 x 16384 B
  __shared__ float red[4];

  const int t = threadIdx.x;
  const int lane = t & 63, wave = t >> 6;
  const int lhalf = lane & 15, quad = lane >> 4;
  const int mt = wave & 1;       // 16-row half
  const int kq = wave >> 1;      // 32-wide K quarter-slice owner within BKS

  // Bijective XCD swizzle: XCD x (= bid%8) gets batch x's 128 blocks,
  // so each XCD's L2 caches exactly one 512 KB VT + 8 KB hsq.
  const int bid = blockIdx.x;
  const int rb = (bid & 7) * (NBLK / 8) + (bid >> 3);
  const int b = rb >> 7;
  const int r2 = rb & 127;
  const int i0 = (r2 >> 1) << 5;
  const int kh0 = (r2 & 1) << 10;

  const float* abase = adj + ((size_t)b << 22);
  const unsigned short* vtbase = vt + (size_t)b * DBLK * N_;
  const float* arow =
      abase + (size_t)(i0 + mt * 16 + lhalf) * N_ + kh0 + kq * 32 + quad * 8;
  const float* hrow = hsq + b * N_ + kh0 + kq * 32 + quad * 8;

  f32x4 acc[8] = {};
  float rs = 0.f, hs = 0.f;
  float4 nA, nB;

  // ---- prologue: stage VT(0), load A(0)
  stage_vt(vtbase, kh0, &lV[0][0], wave, lane);
  nA = *(const float4*)(arow);
  nB = *(const float4*)(arow + 4);
  __syncthreads();

  for (int s = 0; s < NSTEP; ++s) {
    const int cur = s & 1;
    const float4 aA = nA, aB = nB;
    // prefetch step s+1: VT into other buffer, A into regs (in flight
    // across this step's compute; drained by the step-end barrier)
    if (s + 1 < NSTEP) {
      stage_vt(vtbase, kh0 + (s + 1) * BKS, &lV[cur ^ 1][0], wave, lane);
      nA = *(const float4*)(arow + (size_t)(s + 1) * BKS);
      nB = *(const float4*)(arow + (size_t)(s + 1) * BKS + 4);
    }
    // hsq cross terms from in-register A (each adj element owned by exactly
    // one lane: rows via mt/lhalf, cols via kq/quad — no double count)
    {
      const float4 hA = *(const float4*)(hrow + (size_t)s * BKS);
      const float4 hB = *(const float4*)(hrow + (size_t)s * BKS + 4);
      rs += (aA.x + aA.y) + (aA.z + aA.w) + (aB.x + aB.y) + (aB.z + aB.w);
      hs += aA.x * hA.x + aA.y * hA.y + aA.z * hA.z + aA.w * hA.w
          + aB.x * hB.x + aB.y * hB.y + aB.z * hB.z + aB.w * hB.w;
    }
    short8 afrag = pack8(aA, aB);
#pragma unroll
    for (int nt = 0; nt < 8; ++nt) {
      int r = nt * 16 + lhalf;
      int up = (kq * 4 + quad) ^ (r & 7);
      short8 bf = *(const short8*)&lV[cur][r * BKS + up * 8];
      acc[nt] = __builtin_amdgcn_mfma_f32_16x16x32_bf16(afrag, bf, acc[nt], 0, 0, 0);
    }
    __syncthreads();
  }

  // ---- epilogue. MFMA C/D layout: col(n)=lane&15, row(i)=quad*4+rr.
  // part += acc * (-2 emb[i][d]); plus per-lane hsq terms (row = mt*16+lhalf).
  float part = 0.f;
  const float* erow_base = emb + (size_t)b * N_ * D_;
#pragma unroll
  for (int rr = 0; rr < 4; ++rr) {
    int i = i0 + mt * 16 + quad * 4 + rr;
    const float* erow = erow_base + (size_t)i * D_;
#pragma unroll
    for (int nt = 0; nt < 8; ++nt) {
      int d = nt * 16 + lhalf;
      part += acc[nt][rr] * (-2.0f * erow[d]);
    }
  }
  part += hsq[b * N_ + i0 + mt * 16 + lhalf] * rs + hs;
#pragma unroll
  for (int off = 32; off > 0; off >>= 1) part += __shfl_down(part, off);
  if (lane == 0) red[wave] = part;
  __syncthreads();
  if (t == 0)
    atomicAdd(out, (red[0] + red[1] + red[2] + red[3]) *
                       (1.0f / (float)((size_t)B_ * N_)));
}

extern "C" void kernel_launch(void* const* d_in, const int* in_sizes, int n_in,
                              void* d_out, int out_size, void* d_ws, size_t ws_size,
                              hipStream_t stream) {
  const float* adj = (const float*)d_in[0];
  const float* emb = (const float*)d_in[1];
  // ws layout: hsq (64 KiB) | VT bf16 (4 MiB)
  float* hsq = (float*)d_ws;
  unsigned short* vt = (unsigned short*)((char*)d_ws + 65536);

  prep_kernel<<<B_ * (N_ / 64), 256, 0, stream>>>(emb, vt, hsq, (float*)d_out);
  gemm_kernel<<<NBLK, 256, 0, stream>>>(adj, emb, hsq, vt, (float*)d_out);
}